// Round 1
// baseline (52.147 us; speedup 1.0000x reference)
//
#include <hip/hip_runtime.h>

#define C_DIM 256
#define K_NEIGH 32

// ---------------------------------------------------------------------------
// Kernel A: complex linear projection, one 64-lane wave per node.
//   tmp[n] = (Whr[n]·Wr - Whi[n]·Wi + br,  Whr[n]·Wi + Whi[n]·Wr + bi)
// Each lane handles 4 consecutive channels via float4 (16 B/lane coalesced).
// ---------------------------------------------------------------------------
__global__ __launch_bounds__(256) void proj_kernel(
    const float* __restrict__ whr, const float* __restrict__ whi,
    const float* __restrict__ wr,  const float* __restrict__ wi,
    const float* __restrict__ br,  const float* __restrict__ bi,
    float2* __restrict__ tmp, int n_nodes)
{
    const int node = (int)((blockIdx.x * (unsigned)blockDim.x + threadIdx.x) >> 6);
    const int lane = threadIdx.x & 63;
    if (node >= n_nodes) return;

    const float4* whr4 = (const float4*)(whr + (size_t)node * C_DIM);
    const float4* whi4 = (const float4*)(whi + (size_t)node * C_DIM);
    const float4 a = whr4[lane];          // Wh_real[node, 4*lane .. 4*lane+3]
    const float4 b = whi4[lane];          // Wh_imag
    const float4 u = ((const float4*)wr)[lane];   // W_real slice (L2 broadcast)
    const float4 v = ((const float4*)wi)[lane];   // W_imag slice

    // local partials: vr = a·u - b·v ; vi = a·v + b·u
    float vr = a.x*u.x + a.y*u.y + a.z*u.z + a.w*u.w
             - (b.x*v.x + b.y*v.y + b.z*v.z + b.w*v.w);
    float vi = a.x*v.x + a.y*v.y + a.z*v.z + a.w*v.w
             +  b.x*u.x + b.y*u.y + b.z*u.z + b.w*u.w;

    // wave-64 butterfly reduction
    #pragma unroll
    for (int off = 32; off > 0; off >>= 1) {
        vr += __shfl_xor(vr, off, 64);
        vi += __shfl_xor(vi, off, 64);
    }

    if (lane == 0) {
        tmp[node] = make_float2(vr + br[0], vi + bi[0]);
    }
}

// ---------------------------------------------------------------------------
// Kernel B: per-column attention + normalization. One thread per column m.
// Index loads are coalesced (stride m_cols between rows); tmp gathers hit L2.
// ---------------------------------------------------------------------------
__global__ __launch_bounds__(256) void attn_kernel(
    const int* __restrict__ nneg, const float2* __restrict__ tmp,
    float* __restrict__ out, int m_cols)
{
    const int m = blockIdx.x * blockDim.x + threadIdx.x;
    if (m >= m_cols) return;

    const int cidx = nneg[m];             // center index (row 0)
    const float2 c = tmp[cidx];

    float att[K_NEIGH];
    float s = 0.f;
    #pragma unroll
    for (int k = 0; k < K_NEIGH; ++k) {
        const int idx = nneg[(size_t)(k + 1) * m_cols + m];
        const float2 t = tmp[idx];
        const float a = fmaxf(c.x * t.x + c.y * t.y, 0.f);
        att[k] = a;
        s += a;
    }

    const float r = 1.0f / (s + 0.001f);
    #pragma unroll
    for (int k = 0; k < K_NEIGH; ++k) {
        out[(size_t)k * m_cols + m] = att[k] * r;
    }
}

// ---------------------------------------------------------------------------
extern "C" void kernel_launch(void* const* d_in, const int* in_sizes, int n_in,
                              void* d_out, int out_size, void* d_ws, size_t ws_size,
                              hipStream_t stream)
{
    const float* whr = (const float*)d_in[0];
    const float* whi = (const float*)d_in[1];
    const int*   nng = (const int*)d_in[2];
    // d_in[3] = k_neighbors scalar (fixed = 32)
    const float* wr  = (const float*)d_in[4];
    const float* wi  = (const float*)d_in[5];
    const float* br  = (const float*)d_in[6];
    const float* bi  = (const float*)d_in[7];

    const int c_dim   = in_sizes[4];                 // 256
    const int n_nodes = in_sizes[0] / c_dim;         // 100000
    const int m_cols  = in_sizes[2] / (K_NEIGH + 1); // 100000

    float2* tmp = (float2*)d_ws;                     // 2*N floats = 800 KB

    // Kernel A: 4 waves (4 nodes) per 256-thread block
    const int blocksA = (n_nodes + 3) / 4;
    proj_kernel<<<blocksA, 256, 0, stream>>>(whr, whi, wr, wi, br, bi, tmp, n_nodes);

    // Kernel B: one thread per column
    const int blocksB = (m_cols + 255) / 256;
    attn_kernel<<<blocksB, 256, 0, stream>>>(nng, tmp, (float*)d_out, m_cols);
}